// Round 22
// baseline (180.093 us; speedup 1.0000x reference)
//
#include <hip/hip_runtime.h>

#define N_NODES  100000
#define N_EDGES  640000
#define IN_C     128
#define HID_C    256
#define OUT_C    128
#define N_GRAPHS 64
#define CAP      32          // slot capacity per node; P(Poisson(6.4) >= 32) ~ 1e-13

#define NBUK     256                                   // dst-range buckets
#define NPB      ((N_NODES + NBUK - 1) / NBUK)         // 391 nodes per bucket
#define NSTRIPE  8                                     // sub-counters per bucket
#define SCAP     448                                   // stripe capacity (mean 312, +7.7 sigma)
#define BPB      (NSTRIPE * SCAP)                      // 3584 entries per bucket
#define EPB      4096                                  // edges per phaseA block
#define EBLK     ((N_EDGES + EPB - 1) / EPB)           // 157

typedef _Float16 f16;
typedef _Float16 f16x4 __attribute__((ext_vector_type(4)));
typedef _Float16 f16x8 __attribute__((ext_vector_type(8)));
typedef float    f32x4 __attribute__((ext_vector_type(4)));

// ---------------- tiny zero kernel ----------------

__global__ void zero_gcur_kernel(int* __restrict__ g) {
    int i = blockIdx.x * 256 + threadIdx.x;
    if (i < NBUK * NSTRIPE) g[i] = 0;
}

// ---------------- phase A: bucket edges + x->f16 + W^T + init_gs ----------

__global__ __launch_bounds__(256) void phaseA_kernel(
    const int* __restrict__ src, const int* __restrict__ dst,
    int* __restrict__ gcur, int* __restrict__ buckets,
    const float* __restrict__ x, f16* __restrict__ xh,
    const float* __restrict__ W1, f16* __restrict__ Wt1,
    const float* __restrict__ W2, f16* __restrict__ Wt2,
    int* __restrict__ gs) {
    int b = blockIdx.x;
    if (b < EBLK) {                          // bucket 4096 edges
        __shared__ int bcnt[NBUK];
        __shared__ int bbase[NBUK];
        int tid = threadIdx.x;
        int st  = b & (NSTRIPE - 1);
        for (int i = tid; i < NBUK; i += 256) bcnt[i] = 0;
        __syncthreads();
        int e0 = b * EPB + tid * 16;
        bool act = e0 < N_EDGES;             // N_EDGES%16==0 -> all-or-nothing
        int bk[16], pp[16], val[16];
        #pragma unroll
        for (int c = 0; c < 4; ++c) {
            int e = e0 + c * 4;
            int4 dq = act ? *reinterpret_cast<const int4*>(&dst[e]) : make_int4(0,0,0,0);
            int4 sq = act ? *reinterpret_cast<const int4*>(&src[e]) : make_int4(0,0,0,0);
            int dv[4] = {dq.x, dq.y, dq.z, dq.w};
            int sv[4] = {sq.x, sq.y, sq.z, sq.w};
            #pragma unroll
            for (int j = 0; j < 4; ++j) {
                int k = c * 4 + j;
                int bkj = (unsigned)dv[j] / NPB;
                bk[k]  = bkj;
                val[k] = ((dv[j] - bkj * NPB) << 17) | sv[j];
            }
        }
        #pragma unroll
        for (int k = 0; k < 16; ++k)
            pp[k] = act ? atomicAdd(&bcnt[bk[k]], 1) : 0;   // LDS atomic
        __syncthreads();
        if (tid < NBUK) {
            int c = bcnt[tid];
            if (c > 0) bbase[tid] = atomicAdd(&gcur[tid * NSTRIPE + st], c);
        }
        __syncthreads();
        if (act) {
            #pragma unroll
            for (int k = 0; k < 16; ++k) {
                int idx = bbase[bk[k]] + pp[k];
                if (idx < SCAP)              // overflow guard (P ~ 1e-12)
                    buckets[(size_t)bk[k] * BPB + st * SCAP + idx] = val[k];
            }
        }
        return;
    }
    b -= EBLK;
    if (b < 6250) {                          // convert x to f16
        int i = (b * 256 + threadIdx.x) * 8;
        float4 a = *reinterpret_cast<const float4*>(&x[i]);
        float4 c = *reinterpret_cast<const float4*>(&x[i + 4]);
        f16x8 o = { (f16)a.x, (f16)a.y, (f16)a.z, (f16)a.w,
                    (f16)c.x, (f16)c.y, (f16)c.z, (f16)c.w };
        *reinterpret_cast<f16x8*>(&xh[i]) = o;
        return;
    }
    b -= 6250;
    if (b < 128) {                           // W1[K][N] -> Wt1[N][K]
        int idx = b * 256 + threadIdx.x;
        int k = idx / HID_C, n = idx % HID_C;
        Wt1[n * IN_C + k] = (f16)W1[idx];
        return;
    }
    b -= 128;
    if (b < 128) {                           // W2[K][N] -> Wt2[N][K]
        int idx = b * 256 + threadIdx.x;
        int k = idx / OUT_C, n = idx % OUT_C;
        Wt2[n * HID_C + k] = (f16)W2[idx];
        return;
    }
    if (threadIdx.x <= N_GRAPHS) gs[threadIdx.x] = N_NODES;
}
#define PHASEA_BLOCKS (EBLK + 6250 + 128 + 128 + 1)

// ---------------- phase B: per-bucket slot-CSR + meta + find_gs ------------

__global__ __launch_bounds__(256) void phaseB_kernel(
    const int* __restrict__ gcur, const int* __restrict__ buckets,
    int2* __restrict__ meta, int* __restrict__ slots, float* __restrict__ isd,
    const int* __restrict__ batch, int* __restrict__ gs) {
    int b = blockIdx.x;
    if (b < NBUK) {                          // build slot-CSR for my range
        __shared__ int cur[NPB];
        int tid = threadIdx.x;
        int v0 = b * NPB;
        int nv = min(NPB, N_NODES - v0);
        for (int i = tid; i < NPB; i += 256) cur[i] = 0;
        __syncthreads();
        for (int s = 0; s < NSTRIPE; ++s) {
            int n = min(gcur[b * NSTRIPE + s], SCAP);
            const int* seg = &buckets[(size_t)b * BPB + s * SCAP];
            for (int i = tid; i < n; i += 256) {
                int e = seg[i];
                int r = e >> 17;
                int pos = atomicAdd(&cur[r], 1);             // LDS atomic
                if (pos < CAP) slots[(size_t)(v0 + r) * CAP + pos] = e & 0x1FFFF;
            }
        }
        __syncthreads();
        for (int i = tid; i < nv; i += 256) {
            int c = cur[i];
            float iv = rsqrtf((float)c + 1.0f);
            meta[v0 + i] = make_int2(c, __float_as_int(iv));
            isd[v0 + i] = iv;
        }
        return;
    }
    b -= NBUK;                               // node region: find_gs
    int i = b * 256 + threadIdx.x;
    if (i < N_NODES) {
        int bt = batch[i];
        int pb = (i == 0) ? -1 : batch[i - 1];
        for (int g = pb + 1; g <= bt; ++g) gs[g] = i;
    }
}
#define PHASEB_BLOCKS (NBUK + (N_NODES + 255) / 256)

// ---------------- FUSED dense mid-section: t2 = (relu(ax@W1+b1)@W2)*isd ----
// r21 lesson: fusing the gather INTO this kernel kills gather MLP (93us) --
// keep aggs separate. Here: single bounce buffer (same-wave DS ops are
// in-order, so the s-step read completes before the s+1 write issues) cuts
// LDS 54.3->44KB -> 3 blocks/CU (24 waves); launch_bounds(512,2) gives the
// allocator VGPR headroom (r19 spill lesson: never starve the accumulators).

__global__ __launch_bounds__(512, 2) void gemm_fused_kernel(
    const f16* __restrict__ A,      // ax [M][128]
    const f16* __restrict__ Wt1,    // [256][128]
    const f16* __restrict__ Wt2,    // [128][256]
    const float* __restrict__ b1,   // [256]
    const float* __restrict__ isd,  // [M]
    f16* __restrict__ T2, int M) {  // [M][128]
    __shared__ f16 Wl[128 * 132];             // 33.8KB (phase2 uses 64*260 <= this)
    __shared__ f16 bounce[8][16 * 40];        // 10.2KB single per-wave buffer
    int tid  = threadIdx.x;
    int wid  = tid >> 6;
    int lane = tid & 63;
    int l16  = lane & 15;
    int kgrp = lane >> 4;
    int rowbase = blockIdx.x * 128 + wid * 16;
    int arow = rowbase + l16;
    bool okrow = arow < M;

    f16x8 a1[4];
    f16x8 zero = {};
    #pragma unroll
    for (int s = 0; s < 4; ++s)
        a1[s] = okrow ? *reinterpret_cast<const f16x8*>(&A[(size_t)arow * IN_C + s * 32 + kgrp * 8])
                      : zero;

    // ---- phase 1: two 128-col chunks; acc registers local to each chunk ----
    f16x4 p1[16];    // f16 fragments for all 256 cols (32 VGPR)
    #pragma unroll
    for (int c = 0; c < 2; ++c) {
        #pragma unroll
        for (int g = 0; g < 4; ++g) {        // stage 128 cols x 128 k
            int idx = g * 512 + tid;         // 0..2047 granules (16 per col)
            int col = idx >> 4;
            int gg  = idx & 15;
            *reinterpret_cast<f16x8*>(&Wl[col * 132 + gg * 8]) =
                *reinterpret_cast<const f16x8*>(&Wt1[(size_t)(c * 128 + col) * IN_C + gg * 8]);
        }
        __syncthreads();
        f32x4 acc1[8] = {};                  // 32 VGPR, dead after this chunk
        #pragma unroll
        for (int t = 0; t < 8; ++t) {
            #pragma unroll
            for (int s = 0; s < 4; ++s) {
                f16x8 b = *reinterpret_cast<const f16x8*>(
                    &Wl[(t * 16 + l16) * 132 + s * 32 + kgrp * 8]);
                acc1[t] = __builtin_amdgcn_mfma_f32_16x16x32_f16(a1[s], b, acc1[t], 0, 0, 0);
            }
        }
        // bias + relu -> f16 immediately (frees acc1 before next chunk)
        #pragma unroll
        for (int t = 0; t < 8; ++t) {
            float bb = b1[c * 128 + t * 16 + l16];
            #pragma unroll
            for (int j = 0; j < 4; ++j)
                p1[c * 8 + t][j] = (f16)fmaxf(acc1[t][j] + bb, 0.f);
        }
        __syncthreads();
    }
    int crow0 = rowbase + kgrp * 4;
    float sv[4];
    #pragma unroll
    for (int j = 0; j < 4; ++j)
        sv[j] = (crow0 + j < M) ? isd[crow0 + j] : 0.f;

    // ---- phase 2: t2 = p1 @ W2, 2 chunks of 64 output cols ----
    #pragma unroll
    for (int c2 = 0; c2 < 2; ++c2) {
        #pragma unroll
        for (int g = 0; g < 4; ++g) {        // stage 64 cols x 256 k
            int idx = g * 512 + tid;         // 0..2047 granules (32 per col)
            int col = idx >> 5;
            int gg  = idx & 31;
            *reinterpret_cast<f16x8*>(&Wl[col * 260 + gg * 8]) =
                *reinterpret_cast<const f16x8*>(&Wt2[(size_t)(c2 * 64 + col) * HID_C + gg * 8]);
        }
        __syncthreads();
        f32x4 acc2[4] = {};
        #pragma unroll
        for (int s = 0; s < 8; ++s) {        // k-steps over 256
            f16* buf = &bounce[wid][0];      // single buffer: in-order DS ops
            #pragma unroll
            for (int half = 0; half < 2; ++half) {
                int t = 2 * s + half;
                #pragma unroll
                for (int j = 0; j < 4; ++j)
                    buf[(kgrp * 4 + j) * 40 + half * 16 + l16] = p1[t][j];
            }
            f16x8 a2 = *reinterpret_cast<const f16x8*>(&buf[l16 * 40 + kgrp * 8]);
            #pragma unroll
            for (int ct = 0; ct < 4; ++ct) {
                f16x8 b = *reinterpret_cast<const f16x8*>(
                    &Wl[(ct * 16 + l16) * 260 + s * 32 + kgrp * 8]);
                acc2[ct] = __builtin_amdgcn_mfma_f32_16x16x32_f16(a2, b, acc2[ct], 0, 0, 0);
            }
        }
        #pragma unroll
        for (int ct = 0; ct < 4; ++ct) {
            int col = c2 * 64 + ct * 16 + l16;
            #pragma unroll
            for (int j = 0; j < 4; ++j) {
                int row = crow0 + j;
                if (row < M)
                    T2[(size_t)row * OUT_C + col] = (f16)(acc2[ct][j] * sv[j]);
            }
        }
        __syncthreads();
    }
}

// ---------------- aggregation over C=128 f16 channels ----------------
// At the random-gather L3 service-rate floor (~2.5-3 TB/s, r14-r17).

template <bool COEF, bool BIAS_RELU, typename OutT>
__global__ __launch_bounds__(256) void agg_kernel(
    const f16* __restrict__ h, const int2* __restrict__ meta,
    const int* __restrict__ slots, const float* __restrict__ bias,
    OutT* __restrict__ out) {
    constexpr int C = 128;
    int wid  = threadIdx.x >> 6;
    int lane = threadIdx.x & 63;
    int q    = lane >> 4;
    int ln   = lane & 15;
    int vA = blockIdx.x * 8 + wid * 2;
    if (vA >= N_NODES) return;
    int vB = vA + 1;
    bool hasB = vB < N_NODES;
    int baseA = vA * CAP;
    int baseB = hasB ? vB * CAP : 0;

    int2 mA = meta[vA];
    int2 mB = hasB ? meta[vB] : make_int2(0, 0);
    int ra0 = slots[baseA + q];
    int ra1 = slots[baseA + q + 4];
    int rb0 = slots[baseB + q];
    int rb1 = slots[baseB + q + 4];
    f16x8 hvS = {};
    if (q < 2 && (q == 0 || hasB)) {
        int vS = q ? vB : vA;
        hvS = *reinterpret_cast<const f16x8*>(&h[(size_t)vS * C + ln * 8]);
    }

    // UNSIGNED clamp (speculative slots may hold 0xAA poison = negative int)
    int ia0 = ((unsigned)ra0 < N_NODES) ? ra0 : 0;
    int ia1 = ((unsigned)ra1 < N_NODES) ? ra1 : 0;
    int ib0 = ((unsigned)rb0 < N_NODES) ? rb0 : 0;
    int ib1 = ((unsigned)rb1 < N_NODES) ? rb1 : 0;

    f16x8 ha0 = *reinterpret_cast<const f16x8*>(&h[(size_t)ia0 * C + ln * 8]);
    f16x8 ha1 = *reinterpret_cast<const f16x8*>(&h[(size_t)ia1 * C + ln * 8]);
    f16x8 hb0 = *reinterpret_cast<const f16x8*>(&h[(size_t)ib0 * C + ln * 8]);
    f16x8 hb1 = *reinterpret_cast<const f16x8*>(&h[(size_t)ib1 * C + ln * 8]);

    int eA = min(mA.x, CAP);
    int eB = hasB ? min(mB.x, CAP) : 0;
    float ivA = __int_as_float(mA.y);
    float ivB = hasB ? __int_as_float(mB.y) : 0.f;

    bool mA0 = q < eA,     mA1 = q + 4 < eA;
    bool mB0 = q < eB,     mB1 = q + 4 < eB;
    f16 ca0, ca1, cb0, cb1;
    if constexpr (COEF) {
        ca0 = (f16)(mA0 ? __int_as_float(meta[ia0].y) * ivA : 0.f);
        ca1 = (f16)(mA1 ? __int_as_float(meta[ia1].y) * ivA : 0.f);
        cb0 = (f16)(mB0 ? __int_as_float(meta[ib0].y) * ivB : 0.f);
        cb1 = (f16)(mB1 ? __int_as_float(meta[ib1].y) * ivB : 0.f);
    } else {
        ca0 = (f16)(mA0 ? 1.f : 0.f);
        ca1 = (f16)(mA1 ? 1.f : 0.f);
        cb0 = (f16)(mB0 ? 1.f : 0.f);
        cb1 = (f16)(mB1 ? 1.f : 0.f);
    }
    f16x8 acc0 = {}, acc1 = {};
    {
        f16x8 va0 = {ca0, ca0, ca0, ca0, ca0, ca0, ca0, ca0};
        f16x8 va1 = {ca1, ca1, ca1, ca1, ca1, ca1, ca1, ca1};
        f16x8 vb0 = {cb0, cb0, cb0, cb0, cb0, cb0, cb0, cb0};
        f16x8 vb1 = {cb1, cb1, cb1, cb1, cb1, cb1, cb1, cb1};
        acc0 += va0 * ha0;           // v_pk_fma_f16
        acc0 += va1 * ha1;
        acc1 += vb0 * hb0;
        acc1 += vb1 * hb1;
    }

    int tA = 8 + q, tB = 8 + q;
    while (__any((tA < eA) || (tB < eB))) {
        bool nA0 = tA < eA, nA1 = tA + 4 < eA;
        bool nB0 = tB < eB, nB1 = tB + 4 < eB;
        int ja0 = slots[baseA + (nA0 ? tA     : 0)];
        int ja1 = slots[baseA + (nA1 ? tA + 4 : 0)];
        int jb0 = slots[baseB + (nB0 ? tB     : 0)];
        int jb1 = slots[baseB + (nB1 ? tB + 4 : 0)];
        ja0 = ((unsigned)ja0 < N_NODES) ? ja0 : 0;
        ja1 = ((unsigned)ja1 < N_NODES) ? ja1 : 0;
        jb0 = ((unsigned)jb0 < N_NODES) ? jb0 : 0;
        jb1 = ((unsigned)jb1 < N_NODES) ? jb1 : 0;
        f16 da0, da1, db0, db1;
        if constexpr (COEF) {
            da0 = (f16)(nA0 ? __int_as_float(meta[ja0].y) * ivA : 0.f);
            da1 = (f16)(nA1 ? __int_as_float(meta[ja1].y) * ivA : 0.f);
            db0 = (f16)(nB0 ? __int_as_float(meta[jb0].y) * ivB : 0.f);
            db1 = (f16)(nB1 ? __int_as_float(meta[jb1].y) * ivB : 0.f);
        } else {
            da0 = (f16)(nA0 ? 1.f : 0.f);
            da1 = (f16)(nA1 ? 1.f : 0.f);
            db0 = (f16)(nB0 ? 1.f : 0.f);
            db1 = (f16)(nB1 ? 1.f : 0.f);
        }
        f16x8 ga0 = *reinterpret_cast<const f16x8*>(&h[(size_t)ja0 * C + ln * 8]);
        f16x8 ga1 = *reinterpret_cast<const f16x8*>(&h[(size_t)ja1 * C + ln * 8]);
        f16x8 gb0 = *reinterpret_cast<const f16x8*>(&h[(size_t)jb0 * C + ln * 8]);
        f16x8 gb1 = *reinterpret_cast<const f16x8*>(&h[(size_t)jb1 * C + ln * 8]);
        f16x8 wa0 = {da0, da0, da0, da0, da0, da0, da0, da0};
        f16x8 wa1 = {da1, da1, da1, da1, da1, da1, da1, da1};
        f16x8 wb0 = {db0, db0, db0, db0, db0, db0, db0, db0};
        f16x8 wb1 = {db1, db1, db1, db1, db1, db1, db1, db1};
        acc0 += wa0 * ga0;
        acc0 += wa1 * ga1;
        acc1 += wb0 * gb0;
        acc1 += wb1 * gb1;
        tA += 8; tB += 8;
    }

    #pragma unroll
    for (int st = 16; st <= 32; st <<= 1) {
        int4 r0 = __builtin_bit_cast(int4, acc0);
        int4 r1 = __builtin_bit_cast(int4, acc1);
        int4 s0, s1;
        s0.x = __shfl_xor(r0.x, st, 64); s0.y = __shfl_xor(r0.y, st, 64);
        s0.z = __shfl_xor(r0.z, st, 64); s0.w = __shfl_xor(r0.w, st, 64);
        s1.x = __shfl_xor(r1.x, st, 64); s1.y = __shfl_xor(r1.y, st, 64);
        s1.z = __shfl_xor(r1.z, st, 64); s1.w = __shfl_xor(r1.w, st, 64);
        acc0 += __builtin_bit_cast(f16x8, s0);
        acc1 += __builtin_bit_cast(f16x8, s1);
    }
    if (q < 2) {
        bool ok = (q == 0) || hasB;
        if (ok) {
            int v = q ? vB : vA;
            float iv = q ? ivB : ivA;
            f16x8 accv = q ? acc1 : acc0;
            float t[8];
            if constexpr (COEF) {
                float cs = iv * iv;
                #pragma unroll
                for (int i = 0; i < 8; ++i) t[i] = (float)accv[i] + cs * (float)hvS[i];
            } else {
                #pragma unroll
                for (int i = 0; i < 8; ++i) t[i] = iv * ((float)accv[i] + (float)hvS[i]);
            }
            if constexpr (BIAS_RELU) {
                float4 b0 = *reinterpret_cast<const float4*>(&bias[ln * 8]);
                float4 b1 = *reinterpret_cast<const float4*>(&bias[ln * 8 + 4]);
                float bb[8] = {b0.x, b0.y, b0.z, b0.w, b1.x, b1.y, b1.z, b1.w};
                float o[8];
                #pragma unroll
                for (int i = 0; i < 8; ++i)
                    o[i] = fmaxf(t[i] + bb[i], 0.f);
                *reinterpret_cast<float4*>(&out[(size_t)v * C + ln * 8]) =
                    make_float4(o[0], o[1], o[2], o[3]);
                *reinterpret_cast<float4*>(&out[(size_t)v * C + ln * 8 + 4]) =
                    make_float4(o[4], o[5], o[6], o[7]);
            } else {
                f16x8 o;
                #pragma unroll
                for (int i = 0; i < 8; ++i) o[i] = (f16)t[i];
                *reinterpret_cast<f16x8*>(&out[(size_t)v * C + ln * 8]) = o;
            }
        }
    }
}

// ---------------- global mean pool (batch sorted; atomic-free) -------------

#define POOL_PARTS 16
__global__ void pool_partial_kernel(const float* __restrict__ h, const int* __restrict__ gs,
                                    float* __restrict__ psums) {
    int g    = blockIdx.x >> 4;
    int part = blockIdx.x & 15;
    int ch   = threadIdx.x;
    int s = gs[g], e = gs[g + 1];
    float acc = 0.f;
    for (int i = s + part; i < e; i += POOL_PARTS)
        acc += h[(size_t)i * OUT_C + ch];
    psums[(size_t)(g * POOL_PARTS + part) * OUT_C + ch] = acc;
}

__global__ void pool_final_kernel(const float* __restrict__ psums, const int* __restrict__ gs,
                                  float* __restrict__ out2) {
    int g = blockIdx.x, ch = threadIdx.x;
    float acc = 0.f;
    #pragma unroll
    for (int p = 0; p < POOL_PARTS; ++p)
        acc += psums[(size_t)(g * POOL_PARTS + p) * OUT_C + ch];
    int c = gs[g + 1] - gs[g];
    out2[g * OUT_C + ch] = acc / fmaxf((float)c, 1.0f);
}

// ---------------- launch ----------------

extern "C" void kernel_launch(void* const* d_in, const int* in_sizes, int n_in,
                              void* d_out, int out_size, void* d_ws, size_t ws_size,
                              hipStream_t stream) {
    const float* x     = (const float*)d_in[0];
    const int*   ei    = (const int*)d_in[1];
    const int*   src   = ei;
    const int*   dst   = ei + N_EDGES;
    const int*   batch = (const int*)d_in[2];
    const float* W1    = (const float*)d_in[3];
    const float* b1    = (const float*)d_in[4];
    const float* W2    = (const float*)d_in[5];
    const float* b2    = (const float*)d_in[6];

    float* out    = (float*)d_out;
    float* h_out  = out;                                  // [N_NODES, OUT_C]
    float* ge_out = out + (size_t)N_NODES * OUT_C;        // [N_GRAPHS, OUT_C]

    char* wsp = (char*)d_ws;
    auto alloc = [&](size_t bytes) -> char* {
        char* p = wsp;
        wsp += (bytes + 255) & ~(size_t)255;
        return p;
    };
    int2*  meta    = (int2*)alloc((size_t)N_NODES * 8);
    float* isd     = (float*)alloc((size_t)N_NODES * 4);
    int*   slots   = (int*)alloc((size_t)N_NODES * CAP * 4);
    int*   gcur    = (int*)alloc((size_t)NBUK * NSTRIPE * 4);
    int*   buckets = (int*)alloc((size_t)NBUK * BPB * 4);
    int*   gs      = (int*)alloc((size_t)(N_GRAPHS + 1) * 4);
    float* psums   = (float*)alloc((size_t)N_GRAPHS * POOL_PARTS * OUT_C * 4);
    f16*   xh      = (f16*)alloc((size_t)N_NODES * IN_C * 2);
    f16*   ax      = (f16*)alloc((size_t)N_NODES * IN_C * 2);
    f16*   t2      = (f16*)alloc((size_t)N_NODES * OUT_C * 2);
    f16*   Wt1     = (f16*)alloc((size_t)IN_C * HID_C * 2);
    f16*   Wt2     = (f16*)alloc((size_t)HID_C * OUT_C * 2);

    zero_gcur_kernel<<<(NBUK * NSTRIPE + 255) / 256, 256, 0, stream>>>(gcur);

    phaseA_kernel<<<PHASEA_BLOCKS, 256, 0, stream>>>(src, dst, gcur, buckets, x, xh,
                                                     W1, Wt1, W2, Wt2, gs);
    phaseB_kernel<<<PHASEB_BLOCKS, 256, 0, stream>>>(gcur, buckets, meta, slots, isd,
                                                     batch, gs);

    // layer 1 agg: ax = agg(x) with per-edge coef
    agg_kernel<true, false, f16><<<(N_NODES + 7) / 8, 256, 0, stream>>>(
        xh, meta, slots, nullptr, ax);

    // fused dense mid-section: t2 = (relu(ax@W1+b1) @ W2) * isd[row]
    gemm_fused_kernel<<<(N_NODES + 127) / 128, 512, 0, stream>>>(
        ax, Wt1, Wt2, b1, isd, t2, N_NODES);

    // layer 2 agg: h_out = relu(isd_v*(sum + t2_v) + b2)
    agg_kernel<false, true, float><<<(N_NODES + 7) / 8, 256, 0, stream>>>(
        t2, meta, slots, b2, h_out);

    // pool (atomic-free)
    pool_partial_kernel<<<N_GRAPHS * POOL_PARTS, OUT_C, 0, stream>>>(h_out, gs, psums);
    pool_final_kernel<<<N_GRAPHS, OUT_C, 0, stream>>>(psums, gs, ge_out);
}

// Round 23
// 171.606 us; speedup vs baseline: 1.0495x; 1.0495x over previous
//
#include <hip/hip_runtime.h>

#define N_NODES  100000
#define N_EDGES  640000
#define IN_C     128
#define HID_C    256
#define OUT_C    128
#define N_GRAPHS 64
#define CAP      32          // slot capacity per node; P(Poisson(6.4) >= 32) ~ 1e-13

#define NBUK     256                                   // dst-range buckets
#define NPB      ((N_NODES + NBUK - 1) / NBUK)         // 391 nodes per bucket
#define NSTRIPE  8                                     // sub-counters per bucket
#define SCAP     448                                   // stripe capacity (mean 312, +7.7 sigma)
#define BPB      (NSTRIPE * SCAP)                      // 3584 entries per bucket
#define EPB      4096                                  // edges per phaseA block
#define EBLK     ((N_EDGES + EPB - 1) / EPB)           // 157

typedef _Float16 f16;
typedef _Float16 f16x4 __attribute__((ext_vector_type(4)));
typedef _Float16 f16x8 __attribute__((ext_vector_type(8)));
typedef float    f32x4 __attribute__((ext_vector_type(4)));

// ---------------- tiny zero kernel ----------------

__global__ void zero_gcur_kernel(int* __restrict__ g) {
    int i = blockIdx.x * 256 + threadIdx.x;
    if (i < NBUK * NSTRIPE) g[i] = 0;
}

// ---------------- phase A: bucket edges + x->f16 + W^T + init_gs ----------

__global__ __launch_bounds__(256) void phaseA_kernel(
    const int* __restrict__ src, const int* __restrict__ dst,
    int* __restrict__ gcur, int* __restrict__ buckets,
    const float* __restrict__ x, f16* __restrict__ xh,
    const float* __restrict__ W1, f16* __restrict__ Wt1,
    const float* __restrict__ W2, f16* __restrict__ Wt2,
    int* __restrict__ gs) {
    int b = blockIdx.x;
    if (b < EBLK) {                          // bucket 4096 edges
        __shared__ int bcnt[NBUK];
        __shared__ int bbase[NBUK];
        int tid = threadIdx.x;
        int st  = b & (NSTRIPE - 1);
        for (int i = tid; i < NBUK; i += 256) bcnt[i] = 0;
        __syncthreads();
        int e0 = b * EPB + tid * 16;
        bool act = e0 < N_EDGES;             // N_EDGES%16==0 -> all-or-nothing
        int bk[16], pp[16], val[16];
        #pragma unroll
        for (int c = 0; c < 4; ++c) {
            int e = e0 + c * 4;
            int4 dq = act ? *reinterpret_cast<const int4*>(&dst[e]) : make_int4(0,0,0,0);
            int4 sq = act ? *reinterpret_cast<const int4*>(&src[e]) : make_int4(0,0,0,0);
            int dv[4] = {dq.x, dq.y, dq.z, dq.w};
            int sv[4] = {sq.x, sq.y, sq.z, sq.w};
            #pragma unroll
            for (int j = 0; j < 4; ++j) {
                int k = c * 4 + j;
                int bkj = (unsigned)dv[j] / NPB;
                bk[k]  = bkj;
                val[k] = ((dv[j] - bkj * NPB) << 17) | sv[j];
            }
        }
        #pragma unroll
        for (int k = 0; k < 16; ++k)
            pp[k] = act ? atomicAdd(&bcnt[bk[k]], 1) : 0;   // LDS atomic
        __syncthreads();
        if (tid < NBUK) {
            int c = bcnt[tid];
            if (c > 0) bbase[tid] = atomicAdd(&gcur[tid * NSTRIPE + st], c);
        }
        __syncthreads();
        if (act) {
            #pragma unroll
            for (int k = 0; k < 16; ++k) {
                int idx = bbase[bk[k]] + pp[k];
                if (idx < SCAP)              // overflow guard (P ~ 1e-12)
                    buckets[(size_t)bk[k] * BPB + st * SCAP + idx] = val[k];
            }
        }
        return;
    }
    b -= EBLK;
    if (b < 6250) {                          // convert x to f16
        int i = (b * 256 + threadIdx.x) * 8;
        float4 a = *reinterpret_cast<const float4*>(&x[i]);
        float4 c = *reinterpret_cast<const float4*>(&x[i + 4]);
        f16x8 o = { (f16)a.x, (f16)a.y, (f16)a.z, (f16)a.w,
                    (f16)c.x, (f16)c.y, (f16)c.z, (f16)c.w };
        *reinterpret_cast<f16x8*>(&xh[i]) = o;
        return;
    }
    b -= 6250;
    if (b < 128) {                           // W1[K][N] -> Wt1[N][K]
        int idx = b * 256 + threadIdx.x;
        int k = idx / HID_C, n = idx % HID_C;
        Wt1[n * IN_C + k] = (f16)W1[idx];
        return;
    }
    b -= 128;
    if (b < 128) {                           // W2[K][N] -> Wt2[N][K]
        int idx = b * 256 + threadIdx.x;
        int k = idx / OUT_C, n = idx % OUT_C;
        Wt2[n * HID_C + k] = (f16)W2[idx];
        return;
    }
    if (threadIdx.x <= N_GRAPHS) gs[threadIdx.x] = N_NODES;
}
#define PHASEA_BLOCKS (EBLK + 6250 + 128 + 128 + 1)

// ---------------- phase B: per-bucket slot-CSR + meta + find_gs ------------

__global__ __launch_bounds__(256) void phaseB_kernel(
    const int* __restrict__ gcur, const int* __restrict__ buckets,
    int2* __restrict__ meta, int* __restrict__ slots, float* __restrict__ isd,
    const int* __restrict__ batch, int* __restrict__ gs) {
    int b = blockIdx.x;
    if (b < NBUK) {                          // build slot-CSR for my range
        __shared__ int cur[NPB];
        int tid = threadIdx.x;
        int v0 = b * NPB;
        int nv = min(NPB, N_NODES - v0);
        for (int i = tid; i < NPB; i += 256) cur[i] = 0;
        __syncthreads();
        for (int s = 0; s < NSTRIPE; ++s) {
            int n = min(gcur[b * NSTRIPE + s], SCAP);
            const int* seg = &buckets[(size_t)b * BPB + s * SCAP];
            for (int i = tid; i < n; i += 256) {
                int e = seg[i];
                int r = e >> 17;
                int pos = atomicAdd(&cur[r], 1);             // LDS atomic
                if (pos < CAP) slots[(size_t)(v0 + r) * CAP + pos] = e & 0x1FFFF;
            }
        }
        __syncthreads();
        for (int i = tid; i < nv; i += 256) {
            int c = cur[i];
            float iv = rsqrtf((float)c + 1.0f);
            meta[v0 + i] = make_int2(c, __float_as_int(iv));
            isd[v0 + i] = iv;
        }
        return;
    }
    b -= NBUK;                               // node region: find_gs
    int i = b * 256 + threadIdx.x;
    if (i < N_NODES) {
        int bt = batch[i];
        int pb = (i == 0) ? -1 : batch[i - 1];
        for (int g = pb + 1; g <= bt; ++g) gs[g] = i;
    }
}
#define PHASEB_BLOCKS (NBUK + (N_NODES + 255) / 256)

// ---------------- FUSED dense mid-section: t2 = (relu(ax@W1+b1)@W2)*isd ----
// r20: ping-pong bounce + launch_bounds(512,4) -> VGPR squeezed to 64 ->
// residual spills, 40us. r22: single bounce + (512,2) -> no spill (76 VGPR)
// but phase-2 ds chain serialized, 48us. This round: ping-pong AND (512,2)
// -- pipelined bounce with no spills, single-variable completion of the A/B.

__global__ __launch_bounds__(512, 2) void gemm_fused_kernel(
    const f16* __restrict__ A,      // ax [M][128]
    const f16* __restrict__ Wt1,    // [256][128]
    const f16* __restrict__ Wt2,    // [128][256]
    const float* __restrict__ b1,   // [256]
    const float* __restrict__ isd,  // [M]
    f16* __restrict__ T2, int M) {  // [M][128]
    __shared__ f16 Wl[128 * 132];             // 33.8KB (phase2 uses 64*260 <= this)
    __shared__ f16 bounce[8][2][16 * 40];     // 20.5KB per-wave ping-pong
    int tid  = threadIdx.x;
    int wid  = tid >> 6;
    int lane = tid & 63;
    int l16  = lane & 15;
    int kgrp = lane >> 4;
    int rowbase = blockIdx.x * 128 + wid * 16;
    int arow = rowbase + l16;
    bool okrow = arow < M;

    f16x8 a1[4];
    f16x8 zero = {};
    #pragma unroll
    for (int s = 0; s < 4; ++s)
        a1[s] = okrow ? *reinterpret_cast<const f16x8*>(&A[(size_t)arow * IN_C + s * 32 + kgrp * 8])
                      : zero;

    // ---- phase 1: two 128-col chunks; acc registers local to each chunk ----
    f16x4 p1[16];    // f16 fragments for all 256 cols (32 VGPR)
    #pragma unroll
    for (int c = 0; c < 2; ++c) {
        #pragma unroll
        for (int g = 0; g < 4; ++g) {        // stage 128 cols x 128 k
            int idx = g * 512 + tid;         // 0..2047 granules (16 per col)
            int col = idx >> 4;
            int gg  = idx & 15;
            *reinterpret_cast<f16x8*>(&Wl[col * 132 + gg * 8]) =
                *reinterpret_cast<const f16x8*>(&Wt1[(size_t)(c * 128 + col) * IN_C + gg * 8]);
        }
        __syncthreads();
        f32x4 acc1[8] = {};                  // 32 VGPR, dead after this chunk
        #pragma unroll
        for (int t = 0; t < 8; ++t) {
            #pragma unroll
            for (int s = 0; s < 4; ++s) {
                f16x8 b = *reinterpret_cast<const f16x8*>(
                    &Wl[(t * 16 + l16) * 132 + s * 32 + kgrp * 8]);
                acc1[t] = __builtin_amdgcn_mfma_f32_16x16x32_f16(a1[s], b, acc1[t], 0, 0, 0);
            }
        }
        // bias + relu -> f16 immediately (frees acc1 before next chunk)
        #pragma unroll
        for (int t = 0; t < 8; ++t) {
            float bb = b1[c * 128 + t * 16 + l16];
            #pragma unroll
            for (int j = 0; j < 4; ++j)
                p1[c * 8 + t][j] = (f16)fmaxf(acc1[t][j] + bb, 0.f);
        }
        __syncthreads();
    }
    int crow0 = rowbase + kgrp * 4;
    float sv[4];
    #pragma unroll
    for (int j = 0; j < 4; ++j)
        sv[j] = (crow0 + j < M) ? isd[crow0 + j] : 0.f;

    // ---- phase 2: t2 = p1 @ W2, 2 chunks of 64 output cols ----
    #pragma unroll
    for (int c2 = 0; c2 < 2; ++c2) {
        #pragma unroll
        for (int g = 0; g < 4; ++g) {        // stage 64 cols x 256 k
            int idx = g * 512 + tid;         // 0..2047 granules (32 per col)
            int col = idx >> 5;
            int gg  = idx & 31;
            *reinterpret_cast<f16x8*>(&Wl[col * 260 + gg * 8]) =
                *reinterpret_cast<const f16x8*>(&Wt2[(size_t)(c2 * 64 + col) * HID_C + gg * 8]);
        }
        __syncthreads();
        f32x4 acc2[4] = {};
        #pragma unroll
        for (int s = 0; s < 8; ++s) {        // k-steps over 256
            f16* buf = &bounce[wid][s & 1][0];   // ping-pong: write s+1 overlaps MFMA s
            #pragma unroll
            for (int half = 0; half < 2; ++half) {
                int t = 2 * s + half;
                #pragma unroll
                for (int j = 0; j < 4; ++j)
                    buf[(kgrp * 4 + j) * 40 + half * 16 + l16] = p1[t][j];
            }
            f16x8 a2 = *reinterpret_cast<const f16x8*>(&buf[l16 * 40 + kgrp * 8]);
            #pragma unroll
            for (int ct = 0; ct < 4; ++ct) {
                f16x8 b = *reinterpret_cast<const f16x8*>(
                    &Wl[(ct * 16 + l16) * 260 + s * 32 + kgrp * 8]);
                acc2[ct] = __builtin_amdgcn_mfma_f32_16x16x32_f16(a2, b, acc2[ct], 0, 0, 0);
            }
        }
        #pragma unroll
        for (int ct = 0; ct < 4; ++ct) {
            int col = c2 * 64 + ct * 16 + l16;
            #pragma unroll
            for (int j = 0; j < 4; ++j) {
                int row = crow0 + j;
                if (row < M)
                    T2[(size_t)row * OUT_C + col] = (f16)(acc2[ct][j] * sv[j]);
            }
        }
        __syncthreads();
    }
}

// ---------------- aggregation over C=128 f16 channels ----------------
// At the random-gather L3 service-rate floor (~2.5-3 TB/s, r14-r17).

template <bool COEF, bool BIAS_RELU, typename OutT>
__global__ __launch_bounds__(256) void agg_kernel(
    const f16* __restrict__ h, const int2* __restrict__ meta,
    const int* __restrict__ slots, const float* __restrict__ bias,
    OutT* __restrict__ out) {
    constexpr int C = 128;
    int wid  = threadIdx.x >> 6;
    int lane = threadIdx.x & 63;
    int q    = lane >> 4;
    int ln   = lane & 15;
    int vA = blockIdx.x * 8 + wid * 2;
    if (vA >= N_NODES) return;
    int vB = vA + 1;
    bool hasB = vB < N_NODES;
    int baseA = vA * CAP;
    int baseB = hasB ? vB * CAP : 0;

    int2 mA = meta[vA];
    int2 mB = hasB ? meta[vB] : make_int2(0, 0);
    int ra0 = slots[baseA + q];
    int ra1 = slots[baseA + q + 4];
    int rb0 = slots[baseB + q];
    int rb1 = slots[baseB + q + 4];
    f16x8 hvS = {};
    if (q < 2 && (q == 0 || hasB)) {
        int vS = q ? vB : vA;
        hvS = *reinterpret_cast<const f16x8*>(&h[(size_t)vS * C + ln * 8]);
    }

    // UNSIGNED clamp (speculative slots may hold 0xAA poison = negative int)
    int ia0 = ((unsigned)ra0 < N_NODES) ? ra0 : 0;
    int ia1 = ((unsigned)ra1 < N_NODES) ? ra1 : 0;
    int ib0 = ((unsigned)rb0 < N_NODES) ? rb0 : 0;
    int ib1 = ((unsigned)rb1 < N_NODES) ? rb1 : 0;

    f16x8 ha0 = *reinterpret_cast<const f16x8*>(&h[(size_t)ia0 * C + ln * 8]);
    f16x8 ha1 = *reinterpret_cast<const f16x8*>(&h[(size_t)ia1 * C + ln * 8]);
    f16x8 hb0 = *reinterpret_cast<const f16x8*>(&h[(size_t)ib0 * C + ln * 8]);
    f16x8 hb1 = *reinterpret_cast<const f16x8*>(&h[(size_t)ib1 * C + ln * 8]);

    int eA = min(mA.x, CAP);
    int eB = hasB ? min(mB.x, CAP) : 0;
    float ivA = __int_as_float(mA.y);
    float ivB = hasB ? __int_as_float(mB.y) : 0.f;

    bool mA0 = q < eA,     mA1 = q + 4 < eA;
    bool mB0 = q < eB,     mB1 = q + 4 < eB;
    f16 ca0, ca1, cb0, cb1;
    if constexpr (COEF) {
        ca0 = (f16)(mA0 ? __int_as_float(meta[ia0].y) * ivA : 0.f);
        ca1 = (f16)(mA1 ? __int_as_float(meta[ia1].y) * ivA : 0.f);
        cb0 = (f16)(mB0 ? __int_as_float(meta[ib0].y) * ivB : 0.f);
        cb1 = (f16)(mB1 ? __int_as_float(meta[ib1].y) * ivB : 0.f);
    } else {
        ca0 = (f16)(mA0 ? 1.f : 0.f);
        ca1 = (f16)(mA1 ? 1.f : 0.f);
        cb0 = (f16)(mB0 ? 1.f : 0.f);
        cb1 = (f16)(mB1 ? 1.f : 0.f);
    }
    f16x8 acc0 = {}, acc1 = {};
    {
        f16x8 va0 = {ca0, ca0, ca0, ca0, ca0, ca0, ca0, ca0};
        f16x8 va1 = {ca1, ca1, ca1, ca1, ca1, ca1, ca1, ca1};
        f16x8 vb0 = {cb0, cb0, cb0, cb0, cb0, cb0, cb0, cb0};
        f16x8 vb1 = {cb1, cb1, cb1, cb1, cb1, cb1, cb1, cb1};
        acc0 += va0 * ha0;           // v_pk_fma_f16
        acc0 += va1 * ha1;
        acc1 += vb0 * hb0;
        acc1 += vb1 * hb1;
    }

    int tA = 8 + q, tB = 8 + q;
    while (__any((tA < eA) || (tB < eB))) {
        bool nA0 = tA < eA, nA1 = tA + 4 < eA;
        bool nB0 = tB < eB, nB1 = tB + 4 < eB;
        int ja0 = slots[baseA + (nA0 ? tA     : 0)];
        int ja1 = slots[baseA + (nA1 ? tA + 4 : 0)];
        int jb0 = slots[baseB + (nB0 ? tB     : 0)];
        int jb1 = slots[baseB + (nB1 ? tB + 4 : 0)];
        ja0 = ((unsigned)ja0 < N_NODES) ? ja0 : 0;
        ja1 = ((unsigned)ja1 < N_NODES) ? ja1 : 0;
        jb0 = ((unsigned)jb0 < N_NODES) ? jb0 : 0;
        jb1 = ((unsigned)jb1 < N_NODES) ? jb1 : 0;
        f16 da0, da1, db0, db1;
        if constexpr (COEF) {
            da0 = (f16)(nA0 ? __int_as_float(meta[ja0].y) * ivA : 0.f);
            da1 = (f16)(nA1 ? __int_as_float(meta[ja1].y) * ivA : 0.f);
            db0 = (f16)(nB0 ? __int_as_float(meta[jb0].y) * ivB : 0.f);
            db1 = (f16)(nB1 ? __int_as_float(meta[jb1].y) * ivB : 0.f);
        } else {
            da0 = (f16)(nA0 ? 1.f : 0.f);
            da1 = (f16)(nA1 ? 1.f : 0.f);
            db0 = (f16)(nB0 ? 1.f : 0.f);
            db1 = (f16)(nB1 ? 1.f : 0.f);
        }
        f16x8 ga0 = *reinterpret_cast<const f16x8*>(&h[(size_t)ja0 * C + ln * 8]);
        f16x8 ga1 = *reinterpret_cast<const f16x8*>(&h[(size_t)ja1 * C + ln * 8]);
        f16x8 gb0 = *reinterpret_cast<const f16x8*>(&h[(size_t)jb0 * C + ln * 8]);
        f16x8 gb1 = *reinterpret_cast<const f16x8*>(&h[(size_t)jb1 * C + ln * 8]);
        f16x8 wa0 = {da0, da0, da0, da0, da0, da0, da0, da0};
        f16x8 wa1 = {da1, da1, da1, da1, da1, da1, da1, da1};
        f16x8 wb0 = {db0, db0, db0, db0, db0, db0, db0, db0};
        f16x8 wb1 = {db1, db1, db1, db1, db1, db1, db1, db1};
        acc0 += wa0 * ga0;
        acc0 += wa1 * ga1;
        acc1 += wb0 * gb0;
        acc1 += wb1 * gb1;
        tA += 8; tB += 8;
    }

    #pragma unroll
    for (int st = 16; st <= 32; st <<= 1) {
        int4 r0 = __builtin_bit_cast(int4, acc0);
        int4 r1 = __builtin_bit_cast(int4, acc1);
        int4 s0, s1;
        s0.x = __shfl_xor(r0.x, st, 64); s0.y = __shfl_xor(r0.y, st, 64);
        s0.z = __shfl_xor(r0.z, st, 64); s0.w = __shfl_xor(r0.w, st, 64);
        s1.x = __shfl_xor(r1.x, st, 64); s1.y = __shfl_xor(r1.y, st, 64);
        s1.z = __shfl_xor(r1.z, st, 64); s1.w = __shfl_xor(r1.w, st, 64);
        acc0 += __builtin_bit_cast(f16x8, s0);
        acc1 += __builtin_bit_cast(f16x8, s1);
    }
    if (q < 2) {
        bool ok = (q == 0) || hasB;
        if (ok) {
            int v = q ? vB : vA;
            float iv = q ? ivB : ivA;
            f16x8 accv = q ? acc1 : acc0;
            float t[8];
            if constexpr (COEF) {
                float cs = iv * iv;
                #pragma unroll
                for (int i = 0; i < 8; ++i) t[i] = (float)accv[i] + cs * (float)hvS[i];
            } else {
                #pragma unroll
                for (int i = 0; i < 8; ++i) t[i] = iv * ((float)accv[i] + (float)hvS[i]);
            }
            if constexpr (BIAS_RELU) {
                float4 b0 = *reinterpret_cast<const float4*>(&bias[ln * 8]);
                float4 b1 = *reinterpret_cast<const float4*>(&bias[ln * 8 + 4]);
                float bb[8] = {b0.x, b0.y, b0.z, b0.w, b1.x, b1.y, b1.z, b1.w};
                float o[8];
                #pragma unroll
                for (int i = 0; i < 8; ++i)
                    o[i] = fmaxf(t[i] + bb[i], 0.f);
                *reinterpret_cast<float4*>(&out[(size_t)v * C + ln * 8]) =
                    make_float4(o[0], o[1], o[2], o[3]);
                *reinterpret_cast<float4*>(&out[(size_t)v * C + ln * 8 + 4]) =
                    make_float4(o[4], o[5], o[6], o[7]);
            } else {
                f16x8 o;
                #pragma unroll
                for (int i = 0; i < 8; ++i) o[i] = (f16)t[i];
                *reinterpret_cast<f16x8*>(&out[(size_t)v * C + ln * 8]) = o;
            }
        }
    }
}

// ---------------- global mean pool (batch sorted; atomic-free) -------------

#define POOL_PARTS 16
__global__ void pool_partial_kernel(const float* __restrict__ h, const int* __restrict__ gs,
                                    float* __restrict__ psums) {
    int g    = blockIdx.x >> 4;
    int part = blockIdx.x & 15;
    int ch   = threadIdx.x;
    int s = gs[g], e = gs[g + 1];
    float acc = 0.f;
    for (int i = s + part; i < e; i += POOL_PARTS)
        acc += h[(size_t)i * OUT_C + ch];
    psums[(size_t)(g * POOL_PARTS + part) * OUT_C + ch] = acc;
}

__global__ void pool_final_kernel(const float* __restrict__ psums, const int* __restrict__ gs,
                                  float* __restrict__ out2) {
    int g = blockIdx.x, ch = threadIdx.x;
    float acc = 0.f;
    #pragma unroll
    for (int p = 0; p < POOL_PARTS; ++p)
        acc += psums[(size_t)(g * POOL_PARTS + p) * OUT_C + ch];
    int c = gs[g + 1] - gs[g];
    out2[g * OUT_C + ch] = acc / fmaxf((float)c, 1.0f);
}

// ---------------- launch ----------------

extern "C" void kernel_launch(void* const* d_in, const int* in_sizes, int n_in,
                              void* d_out, int out_size, void* d_ws, size_t ws_size,
                              hipStream_t stream) {
    const float* x     = (const float*)d_in[0];
    const int*   ei    = (const int*)d_in[1];
    const int*   src   = ei;
    const int*   dst   = ei + N_EDGES;
    const int*   batch = (const int*)d_in[2];
    const float* W1    = (const float*)d_in[3];
    const float* b1    = (const float*)d_in[4];
    const float* W2    = (const float*)d_in[5];
    const float* b2    = (const float*)d_in[6];

    float* out    = (float*)d_out;
    float* h_out  = out;                                  // [N_NODES, OUT_C]
    float* ge_out = out + (size_t)N_NODES * OUT_C;        // [N_GRAPHS, OUT_C]

    char* wsp = (char*)d_ws;
    auto alloc = [&](size_t bytes) -> char* {
        char* p = wsp;
        wsp += (bytes + 255) & ~(size_t)255;
        return p;
    };
    int2*  meta    = (int2*)alloc((size_t)N_NODES * 8);
    float* isd     = (float*)alloc((size_t)N_NODES * 4);
    int*   slots   = (int*)alloc((size_t)N_NODES * CAP * 4);
    int*   gcur    = (int*)alloc((size_t)NBUK * NSTRIPE * 4);
    int*   buckets = (int*)alloc((size_t)NBUK * BPB * 4);
    int*   gs      = (int*)alloc((size_t)(N_GRAPHS + 1) * 4);
    float* psums   = (float*)alloc((size_t)N_GRAPHS * POOL_PARTS * OUT_C * 4);
    f16*   xh      = (f16*)alloc((size_t)N_NODES * IN_C * 2);
    f16*   ax      = (f16*)alloc((size_t)N_NODES * IN_C * 2);
    f16*   t2      = (f16*)alloc((size_t)N_NODES * OUT_C * 2);
    f16*   Wt1     = (f16*)alloc((size_t)IN_C * HID_C * 2);
    f16*   Wt2     = (f16*)alloc((size_t)HID_C * OUT_C * 2);

    zero_gcur_kernel<<<(NBUK * NSTRIPE + 255) / 256, 256, 0, stream>>>(gcur);

    phaseA_kernel<<<PHASEA_BLOCKS, 256, 0, stream>>>(src, dst, gcur, buckets, x, xh,
                                                     W1, Wt1, W2, Wt2, gs);
    phaseB_kernel<<<PHASEB_BLOCKS, 256, 0, stream>>>(gcur, buckets, meta, slots, isd,
                                                     batch, gs);

    // layer 1 agg: ax = agg(x) with per-edge coef
    agg_kernel<true, false, f16><<<(N_NODES + 7) / 8, 256, 0, stream>>>(
        xh, meta, slots, nullptr, ax);

    // fused dense mid-section: t2 = (relu(ax@W1+b1) @ W2) * isd[row]
    gemm_fused_kernel<<<(N_NODES + 127) / 128, 512, 0, stream>>>(
        ax, Wt1, Wt2, b1, isd, t2, N_NODES);

    // layer 2 agg: h_out = relu(isd_v*(sum + t2_v) + b2)
    agg_kernel<false, true, float><<<(N_NODES + 7) / 8, 256, 0, stream>>>(
        t2, meta, slots, b2, h_out);

    // pool (atomic-free)
    pool_partial_kernel<<<N_GRAPHS * POOL_PARTS, OUT_C, 0, stream>>>(h_out, gs, psums);
    pool_final_kernel<<<N_GRAPHS, OUT_C, 0, stream>>>(psums, gs, ge_out);
}